// Round 5
// baseline (349.831 us; speedup 1.0000x reference)
//
#include <hip/hip_runtime.h>

#define T_ 30
#define H_ 41
#define WD_ 2048
#define NSEC 9
#define FM 50
#define WP 502
#define THRESH 23.0f
#define POOLED_SIZE (NSEC * T_ * FM * WP)   // 6,777,000
#define MARGIN 0.0078125f                   // 2^-7 >= worst-case bf16-split error
#define NFRAG 18432                         // 9 sec * 64 fm * 32 tap-octets

typedef short short8 __attribute__((ext_vector_type(8)));
typedef float f32x4 __attribute__((ext_vector_type(4)));

__device__ __forceinline__ unsigned bf16_rne(float f) {
    unsigned u = __float_as_uint(f);
    return (u + 0x7fffu + ((u >> 16) & 1u)) >> 16;
}

// ---------------- prep: W -> MFMA-ready bf16 hi/lo fragments in ws --------
__global__ __launch_bounds__(256) void prep_kernel(
    const float* __restrict__ Wg, int* __restrict__ wsi,
    uint4* __restrict__ wfh, uint4* __restrict__ wfl)
{
    const int gid = blockIdx.x * 256 + threadIdx.x;
    if (gid < NSEC) wsi[gid] = 0x7fffffff;
    if (gid >= NFRAG) return;
    const int blk = gid & 31;
    const int fm  = (gid >> 5) & 63;
    const int sec = gid >> 11;
    const int t0  = blk * 8;
    const bool valid = (t0 < 240) && (fm < FM);
    unsigned hh[4], ll[4];
    const float* wp = Wg + ((size_t)sec * FM + (valid ? fm : 0)) * 240 + (valid ? t0 : 0);
    float4 wa = *reinterpret_cast<const float4*>(wp);
    float4 wb = *reinterpret_cast<const float4*>(wp + 4);
    float f[8] = {wa.x, wa.y, wa.z, wa.w, wb.x, wb.y, wb.z, wb.w};
#pragma unroll
    for (int i = 0; i < 4; ++i) {
        float f0 = valid ? f[2 * i] : 0.f;
        float f1 = valid ? f[2 * i + 1] : 0.f;
        unsigned h0 = bf16_rne(f0), h1 = bf16_rne(f1);
        float hf0 = __uint_as_float(h0 << 16), hf1 = __uint_as_float(h1 << 16);
        unsigned l0 = bf16_rne(f0 - hf0), l1 = bf16_rne(f1 - hf1);
        hh[i] = (h1 << 16) | h0;
        ll[i] = (l1 << 16) | l0;
    }
    wfh[gid] = *reinterpret_cast<uint4*>(hh);
    wfl[gid] = *reinterpret_cast<uint4*>(ll);
}

// ---------------- Kernel A: split-bf16 MFMA conv + fire + pool + argmin ----
// R14: 2-plane + register-window restructure of R13.
//  res = Sp + off (Sp in {0,1}, off in {0,2,4,6}). An off-by-2-ELEM (4B)
//  window into two adjacent b128 reads is dword-aligned -> frag for off
//  2/4/6 is a compile-time shufflevector, zero extra LDS traffic.
//  - LDS: 2 shift planes instead of 4 -> 16,384 B total (planes 15,360 +
//    sred 1,024). Statically 10 blocks/CU by LDS; launch_bounds(256,4).
//  - DS reads/wave: 768 -> 256 (4 aligned b128 per kk serve 4 res).
//  - 4 independent acc chains per (ft,Sp); same MFMA count and identical
//    per-res accumulation order as R13 -> bitwise-same pots, absmax 0.
//  - XOR swizzle retained: elem col ^ ((row&7)<<3), rows padded to 192.
template <bool PRE>
__global__ __launch_bounds__(256, 4) void conv_pool_kernel(
    const float* __restrict__ x, const float* __restrict__ Wg,
    const uint4* __restrict__ wfh, const uint4* __restrict__ wfl,
    float* __restrict__ out, int* __restrict__ keys)
{
    __shared__ __align__(16) unsigned short xh[2][10][192];   // 7.5 KB
    __shared__ __align__(16) unsigned short xl[2][10][192];   // 7.5 KB
    __shared__ int sred[256];                                  // lmask, then red

    const int b       = blockIdx.x;
    const int coltile = b & 15;
    const int tt      = (b >> 4) % T_;
    const int sec     = b / 480;
    const int w0      = coltile * 128;     // pot-col base
    const int rowbase = 4 * sec;
    const int tid     = threadIdx.x;

    // ---- stage x: 10 rows x 176 cols -> hi/lo u16, 2 shifted planes, swizzled ----
    for (int i = tid; i < 440; i += 256) {
        const int row = i / 44;
        const int c4  = i % 44;
        const int grow = (rowbase + row < H_) ? rowbase + row : H_ - 1;
        const int gc   = w0 + 4 * c4;
        float4 v;
        if (gc + 3 < WD_) {
            v = *reinterpret_cast<const float4*>(x + ((size_t)tt * H_ + grow) * WD_ + gc);
        } else {
            v.x = v.y = v.z = v.w = 0.f;
        }
        float f[4] = {v.x, v.y, v.z, v.w};
        unsigned short hq[4], lq[4];
#pragma unroll
        for (int e = 0; e < 4; ++e) {
            unsigned h = bf16_rne(f[e]);
            float hf = __uint_as_float(h << 16);
            unsigned l = bf16_rne(f[e] - hf);
            hq[e] = (unsigned short)h;
            lq[e] = (unsigned short)l;
        }
        const int xr = (row & 7) << 3;
#pragma unroll
        for (int S = 0; S < 2; ++S)
#pragma unroll
            for (int e = 0; e < 4; ++e) {
                const int j = 4 * c4 + e - S;
                if (j >= 0 && j < 176) {
                    xh[S][row][j ^ xr] = hq[e];
                    xl[S][row][j ^ xr] = lq[e];
                }
            }
    }
    __syncthreads();

    const int L    = tid & 63;
    const int j_p  = tid >> 6;       // wave id = pot row
    const int q    = L >> 4;         // quad
    const int n16  = L & 15;         // A: m-index; B: fm-index

    // per-kk tap geometry (tau0 = 32kk + 8q -> weight row r, col c0), swizzled
    // pA  -> elems [s,   s+8)   (16B-aligned)
    // pA2 -> elems [s+8, s+16)  (16B-aligned)
    int pA[8], pA2[8];
#pragma unroll
    for (int kk = 0; kk < 8; ++kk) {
        const int t0 = 32 * kk + 8 * q;
        const int r  = t0 / 40;
        const int c0 = t0 - 40 * r;          // multiple of 8
        const int row = j_p + r;
        const int xr  = (row & 7) << 3;
        const int s   = c0 + 8 * n16;        // multiple of 8, <= 152
        pA[kk]  = row * 192 + (s ^ xr);
        pA2[kk] = row * 192 + ((s + 8) ^ xr);
    }

    unsigned mask = 0;

#pragma unroll 1
    for (int ft = 0; ft < 4; ++ft) {
        const int fm = ft * 16 + n16;
        short8 wh[8], wl[8];
        if (PRE) {
            const int fb = (sec * 64 + ft * 16 + n16) * 32 + q;
#pragma unroll
            for (int kk = 0; kk < 8; ++kk) {
                uint4 hu = wfh[fb + 4 * kk];
                uint4 lu = wfl[fb + 4 * kk];
                union { uint4 u; short8 s; } c1, c2;
                c1.u = hu; c2.u = lu;
                wh[kk] = c1.s; wl[kk] = c2.s;
            }
        } else {
            // fallback: in-kernel build (used only if ws too small)
#pragma unroll
            for (int kk = 0; kk < 8; ++kk) {
                const int t0 = 32 * kk + 8 * q;
                const bool wvalid = (t0 < 240) && (fm < FM);
                const float* wp = Wg + (size_t)sec * FM * 240 +
                                  (size_t)(wvalid ? fm : 0) * 240 + (wvalid ? t0 : 0);
                float4 wa = *reinterpret_cast<const float4*>(wp);
                float4 wb = *reinterpret_cast<const float4*>(wp + 4);
                float f[8] = {wa.x, wa.y, wa.z, wa.w, wb.x, wb.y, wb.z, wb.w};
                unsigned hh[4], ll[4];
#pragma unroll
                for (int i = 0; i < 4; ++i) {
                    float f0 = wvalid ? f[2 * i] : 0.f;
                    float f1 = wvalid ? f[2 * i + 1] : 0.f;
                    unsigned h0 = bf16_rne(f0), h1 = bf16_rne(f1);
                    float hf0 = __uint_as_float(h0 << 16), hf1 = __uint_as_float(h1 << 16);
                    unsigned l0 = bf16_rne(f0 - hf0), l1 = bf16_rne(f1 - hf1);
                    hh[i] = (h1 << 16) | h0;
                    ll[i] = (l1 << 16) | l0;
                }
                wh[kk] = *reinterpret_cast<short8*>(hh);
                wl[kk] = *reinterpret_cast<short8*>(ll);
            }
        }

#pragma unroll 1
        for (int Sp = 0; Sp < 2; ++Sp) {
            const unsigned short* hb = &xh[Sp][0][0];
            const unsigned short* lb = &xl[Sp][0][0];

            f32x4 acc0 = {0.f, 0.f, 0.f, 0.f};   // off 0 -> res = Sp
            f32x4 acc1 = {0.f, 0.f, 0.f, 0.f};   // off 2 -> res = Sp + 2
            f32x4 acc2 = {0.f, 0.f, 0.f, 0.f};   // off 4 -> res = Sp + 4
            f32x4 acc3 = {0.f, 0.f, 0.f, 0.f};   // off 6 -> res = Sp + 6
#pragma unroll
            for (int kk = 0; kk < 8; ++kk) {
                short8 h0 = *reinterpret_cast<const short8*>(hb + pA[kk]);
                short8 h1 = *reinterpret_cast<const short8*>(hb + pA2[kk]);
                short8 l0 = *reinterpret_cast<const short8*>(lb + pA[kk]);
                short8 l1 = *reinterpret_cast<const short8*>(lb + pA2[kk]);

                acc0 = __builtin_amdgcn_mfma_f32_16x16x32_bf16(h0, wh[kk], acc0, 0, 0, 0);
                acc0 = __builtin_amdgcn_mfma_f32_16x16x32_bf16(l0, wh[kk], acc0, 0, 0, 0);
                acc0 = __builtin_amdgcn_mfma_f32_16x16x32_bf16(h0, wl[kk], acc0, 0, 0, 0);

                short8 f2h = __builtin_shufflevector(h0, h1, 2, 3, 4, 5, 6, 7, 8, 9);
                short8 f2l = __builtin_shufflevector(l0, l1, 2, 3, 4, 5, 6, 7, 8, 9);
                acc1 = __builtin_amdgcn_mfma_f32_16x16x32_bf16(f2h, wh[kk], acc1, 0, 0, 0);
                acc1 = __builtin_amdgcn_mfma_f32_16x16x32_bf16(f2l, wh[kk], acc1, 0, 0, 0);
                acc1 = __builtin_amdgcn_mfma_f32_16x16x32_bf16(f2h, wl[kk], acc1, 0, 0, 0);

                short8 f4h = __builtin_shufflevector(h0, h1, 4, 5, 6, 7, 8, 9, 10, 11);
                short8 f4l = __builtin_shufflevector(l0, l1, 4, 5, 6, 7, 8, 9, 10, 11);
                acc2 = __builtin_amdgcn_mfma_f32_16x16x32_bf16(f4h, wh[kk], acc2, 0, 0, 0);
                acc2 = __builtin_amdgcn_mfma_f32_16x16x32_bf16(f4l, wh[kk], acc2, 0, 0, 0);
                acc2 = __builtin_amdgcn_mfma_f32_16x16x32_bf16(f4h, wl[kk], acc2, 0, 0, 0);

                short8 f6h = __builtin_shufflevector(h0, h1, 6, 7, 8, 9, 10, 11, 12, 13);
                short8 f6l = __builtin_shufflevector(l0, l1, 6, 7, 8, 9, 10, 11, 12, 13);
                acc3 = __builtin_amdgcn_mfma_f32_16x16x32_bf16(f6h, wh[kk], acc3, 0, 0, 0);
                acc3 = __builtin_amdgcn_mfma_f32_16x16x32_bf16(f6l, wh[kk], acc3, 0, 0, 0);
                acc3 = __builtin_amdgcn_mfma_f32_16x16x32_bf16(f6h, wl[kk], acc3, 0, 0, 0);
            }

            // ---- epilogue: repair borderline, set pool bits (4 res) ----
            auto epilogue = [&](const f32x4& acc, const int res) {
#pragma unroll
                for (int reg = 0; reg < 4; ++reg) {
                    float v = acc[reg];
                    const int m   = q * 4 + reg;
                    const int pcg = w0 + res + 8 * m;     // global pot col
                    const bool valid = (fm < FM) && (pcg <= 2007);
                    if (valid && __builtin_fabsf(v - THRESH) < MARGIN) {
                        float pot = 0.f;
#pragma unroll 1
                        for (int r2 = 0; r2 < 6; ++r2) {
                            const float* xr2 = x + ((size_t)tt * H_ + rowbase + j_p + r2) * WD_ + pcg;
                            const float* wr = Wg + (size_t)sec * FM * 240 + (size_t)fm * 240 + r2 * 40;
#pragma unroll 1
                            for (int c = 0; c < 40; ++c)
                                pot = fmaf(xr2[c], wr[c], pot);
                        }
                        v = pot;
                    }
                    if (v > THRESH)
                        mask |= 1u << (reg * 8 + ft * 2 + (res >> 2));
                }
            };
            epilogue(acc0, Sp);
            epilogue(acc1, Sp + 2);
            epilogue(acc2, Sp + 4);
            epilogue(acc3, Sp + 6);
        }
    }

    unsigned* lmask = reinterpret_cast<unsigned*>(sred);
    lmask[j_p * 64 + L] = mask;
    __syncthreads();

    // ---- cross-wave OR + pooled write + fused first-spike argmin ----
    int mykey = 0x7fffffff;
    for (int e = tid; e < 2048; e += 256) {
        const int fmo = e >> 5, p = e & 31;
        const int m = p >> 1, rg = p & 1, ftc = fmo >> 4, fn = fmo & 15;
        const int lane = (m >> 2) * 16 + fn;
        const int bitpos = (m & 3) * 8 + ftc * 2 + rg;
        const unsigned bits = lmask[0 * 64 + lane] | lmask[1 * 64 + lane] |
                              lmask[2 * 64 + lane] | lmask[3 * 64 + lane];
        const int pg = coltile * 32 + p;
        const int spk = (bits >> bitpos) & 1u;
        if (fmo < FM && pg < WP) {
            out[((size_t)(sec * T_ + tt) * FM + fmo) * WP + pg] = spk ? 1.0f : 0.0f;
            if (spk) mykey = min(mykey, fmo * WP + pg);   // section-flat idx
        }
    }
    __syncthreads();                     // protect lmask -> red reuse
    sred[tid] = mykey;
    __syncthreads();
    for (int s = 128; s > 0; s >>= 1) {
        if (tid < s) sred[tid] = min(sred[tid], sred[tid + s]);
        __syncthreads();
    }
    if (tid == 0 && sred[0] != 0x7fffffff)
        atomicMin(&keys[sec], (tt << 15) | sred[0]);
}

// ---------------- init (fallback only) ----------------
__global__ void init_kernel(int* __restrict__ ws)
{
    if (threadIdx.x < NSEC) ws[threadIdx.x] = 0x7fffffff;
}

// ---------------- Kernel D: finalize winners ----------------
__global__ void finalize_kernel(const int* __restrict__ ws, float* __restrict__ out)
{
    const int i = threadIdx.x;
    if (i < NSEC) {
        const int key = ws[i];
        float feat;
        if (key == 0x7fffffff) feat = -1.0f;
        else                   feat = (float)((key & 32767) / WP);
        out[POOLED_SIZE + i] = feat;
    }
}

extern "C" void kernel_launch(void* const* d_in, const int* in_sizes, int n_in,
                              void* d_out, int out_size, void* d_ws, size_t ws_size,
                              hipStream_t stream) {
    const float* x  = (const float*)d_in[0];
    const float* Wg = (const float*)d_in[1];
    float* out = (float*)d_out;
    int*   wsi = (int*)d_ws;
    uint4* wfh = (uint4*)((char*)d_ws + 256);
    uint4* wfl = wfh + NFRAG;

    const bool pre = ws_size >= 256 + (size_t)NFRAG * 16 * 2;   // 590 KB
    if (pre) {
        prep_kernel<<<dim3(72), dim3(256), 0, stream>>>(Wg, wsi, wfh, wfl);
        conv_pool_kernel<true><<<dim3(4320), dim3(256), 0, stream>>>(x, Wg, wfh, wfl, out, wsi);
    } else {
        init_kernel<<<dim3(1), dim3(64), 0, stream>>>(wsi);
        conv_pool_kernel<false><<<dim3(4320), dim3(256), 0, stream>>>(x, Wg, wfh, wfl, out, wsi);
    }
    finalize_kernel<<<dim3(1), dim3(16), 0, stream>>>(wsi, out);
}

// Round 6
// 183.923 us; speedup vs baseline: 1.9021x; 1.9021x over previous
//
#include <hip/hip_runtime.h>

#define T_ 30
#define H_ 41
#define WD_ 2048
#define NSEC 9
#define FM 50
#define WP 502
#define THRESH 23.0f
#define POOLED_SIZE (NSEC * T_ * FM * WP)   // 6,777,000
#define MARGIN 0.125f                       // >> realistic f16 max error (~0.02)
#define NFRAG 18432                         // 9 sec * 64 fm * 32 tap-octets

typedef _Float16 half8 __attribute__((ext_vector_type(8)));
typedef _Float16 half4v __attribute__((ext_vector_type(4)));
typedef float f32x4 __attribute__((ext_vector_type(4)));

__device__ __forceinline__ unsigned short f16_bits(float f) {
    union { _Float16 h; unsigned short s; } u;
    u.h = (_Float16)f;
    return u.s;
}

// ---------------- prep: W -> MFMA-ready f16 fragments in ws ---------------
__global__ __launch_bounds__(256) void prep_kernel(
    const float* __restrict__ Wg, int* __restrict__ wsi,
    uint4* __restrict__ wfh)
{
    const int gid = blockIdx.x * 256 + threadIdx.x;
    if (gid < NSEC) wsi[gid] = 0x7fffffff;
    if (gid >= NFRAG) return;
    const int blk = gid & 31;
    const int fm  = (gid >> 5) & 63;
    const int sec = gid >> 11;
    const int t0  = blk * 8;
    const bool valid = (t0 < 240) && (fm < FM);
    const float* wp = Wg + ((size_t)sec * FM + (valid ? fm : 0)) * 240 + (valid ? t0 : 0);
    float4 wa = *reinterpret_cast<const float4*>(wp);
    float4 wb = *reinterpret_cast<const float4*>(wp + 4);
    float f[8] = {wa.x, wa.y, wa.z, wa.w, wb.x, wb.y, wb.z, wb.w};
    unsigned hh[4];
#pragma unroll
    for (int i = 0; i < 4; ++i) {
        unsigned h0 = f16_bits(valid ? f[2 * i] : 0.f);
        unsigned h1 = f16_bits(valid ? f[2 * i + 1] : 0.f);
        hh[i] = (h1 << 16) | h0;
    }
    wfh[gid] = *reinterpret_cast<uint4*>(hh);
}

// ---------------- Kernel A: f16 single-term MFMA conv + fire/pool/argmin --
// R15: replace the 3-term split-bf16 (R8/R13, 768 MFMA + 768 ds_read/wave)
// with single-term f16 MFMA (f16 has 11 mantissa bits; x,w fit range):
//   MFMA/wave 768->256, DS reads/wave halve (no lo planes), LDS 31.7->16.4KB,
//   staging quantize = 1 cvt/elem. Error <= 2^-10 * Sum x|w| (~0.02 realistic
//   max) << MARGIN 0.125; borderline pots repaired by a WAVE-PARALLEL fp32
//   recompute (ballot -> 64 lanes x 4 taps + shfl_xor butterfly, ~600cyc)
//   instead of the old serial 240-tap per-lane loop (~70kcyc).
// Rationale: R8..R14 all land 316-420us with wall ~= MFMA+VALU+DS issue sum
// (pipes serialized at ~2.6 resident blocks/CU) -> only cutting TOTAL issued
// cycles moves the needle. Keeps R13's proven pA/pB geometry + XOR swizzle.
template <bool PRE>
__global__ __launch_bounds__(256) void conv_pool_kernel(
    const float* __restrict__ x, const float* __restrict__ Wg,
    const uint4* __restrict__ wfh,
    float* __restrict__ out, int* __restrict__ keys)
{
    __shared__ __align__(16) unsigned short xh[4][10][192];   // 15 KB (f16)
    __shared__ int sred[256];                                  // lmask, then red

    const int b       = blockIdx.x;
    const int coltile = b & 15;
    const int tt      = (b >> 4) % T_;
    const int sec     = b / 480;
    const int w0      = coltile * 128;     // pot-col base
    const int rowbase = 4 * sec;
    const int tid     = threadIdx.x;

    // ---- stage x: 10 rows x 176 cols -> f16, 4 shifted planes, swizzled ----
    for (int i = tid; i < 440; i += 256) {
        const int row = i / 44;
        const int c4  = i % 44;
        const int grow = (rowbase + row < H_) ? rowbase + row : H_ - 1;
        const int gc   = w0 + 4 * c4;
        float4 v;
        if (gc + 3 < WD_) {
            v = *reinterpret_cast<const float4*>(x + ((size_t)tt * H_ + grow) * WD_ + gc);
        } else {
            v.x = v.y = v.z = v.w = 0.f;
        }
        float f[4] = {v.x, v.y, v.z, v.w};
        unsigned short hq[4];
#pragma unroll
        for (int e = 0; e < 4; ++e) hq[e] = f16_bits(f[e]);
        const int xr = (row & 7) << 3;
#pragma unroll
        for (int S = 0; S < 4; ++S)
#pragma unroll
            for (int e = 0; e < 4; ++e) {
                const int j = 4 * c4 + e - S;
                if (j >= 0 && j < 176) xh[S][row][j ^ xr] = hq[e];
            }
    }
    __syncthreads();

    const int L    = tid & 63;
    const int j_p  = tid >> 6;       // wave id = pot row
    const int q    = L >> 4;         // quad (K-octet)
    const int n16  = L & 15;         // A: m-index; B: fm-index

    // per-kk tap geometry (tau0 = 32kk + 8q -> weight row r, col c0), swizzled
    int pA[8], pB[8];
#pragma unroll
    for (int kk = 0; kk < 8; ++kk) {
        const int t0 = 32 * kk + 8 * q;
        const int r  = t0 / 40;
        const int c0 = t0 - 40 * r;          // multiple of 8
        const int row = j_p + r;
        const int xr  = (row & 7) << 3;
        const int s   = c0 + 8 * n16;        // multiple of 8, <= 152
        pA[kk] = row * 192 + (s ^ xr);       // slot [s, s+8)
        pB[kk] = row * 192 + ((s + 8) ^ xr); // slot [s+8, s+16)
    }

    unsigned mask = 0;

#pragma unroll 1
    for (int ft = 0; ft < 4; ++ft) {
        const int fm = ft * 16 + n16;
        half8 wh[8];
        if (PRE) {
            const int fb = (sec * 64 + ft * 16 + n16) * 32 + q;
#pragma unroll
            for (int kk = 0; kk < 8; ++kk) {
                union { uint4 u; half8 h; } c1;
                c1.u = wfh[fb + 4 * kk];
                wh[kk] = c1.h;
            }
        } else {
            // fallback: in-kernel build (used only if ws too small)
#pragma unroll
            for (int kk = 0; kk < 8; ++kk) {
                const int t0 = 32 * kk + 8 * q;
                const bool wvalid = (t0 < 240) && (fm < FM);
                const float* wp = Wg + (size_t)sec * FM * 240 +
                                  (size_t)(wvalid ? fm : 0) * 240 + (wvalid ? t0 : 0);
                float4 wa = *reinterpret_cast<const float4*>(wp);
                float4 wb = *reinterpret_cast<const float4*>(wp + 4);
                float f[8] = {wa.x, wa.y, wa.z, wa.w, wb.x, wb.y, wb.z, wb.w};
                union { unsigned u[4]; half8 h; } c1;
#pragma unroll
                for (int i = 0; i < 4; ++i) {
                    unsigned h0 = f16_bits(wvalid ? f[2 * i] : 0.f);
                    unsigned h1 = f16_bits(wvalid ? f[2 * i + 1] : 0.f);
                    c1.u[i] = (h1 << 16) | h0;
                }
                wh[kk] = c1.h;
            }
        }

#pragma unroll 1
        for (int S = 0; S < 4; ++S) {
            const unsigned short* hb = &xh[S][0][0];

            f32x4 acc0 = {0.f, 0.f, 0.f, 0.f};   // res = S     (off 0)
            f32x4 acc1 = {0.f, 0.f, 0.f, 0.f};   // res = S + 4 (off 4)
#pragma unroll
            for (int kk = 0; kk < 8; ++kk) {
                half8 ah0 = *reinterpret_cast<const half8*>(hb + pA[kk]);
                half4v h0 = *reinterpret_cast<const half4v*>(hb + pA[kk] + 4);
                half4v h1 = *reinterpret_cast<const half4v*>(hb + pB[kk]);
                half8 ah1 = __builtin_shufflevector(h0, h1, 0, 1, 2, 3, 4, 5, 6, 7);
                acc0 = __builtin_amdgcn_mfma_f32_16x16x32_f16(ah0, wh[kk], acc0, 0, 0, 0);
                acc1 = __builtin_amdgcn_mfma_f32_16x16x32_f16(ah1, wh[kk], acc1, 0, 0, 0);
            }

            // ---- epilogue: wave-parallel repair of borderline, pool bits ----
            auto epilogue = [&](const f32x4& acc, const int res) {
#pragma unroll
                for (int reg = 0; reg < 4; ++reg) {
                    float v = acc[reg];
                    const int m   = q * 4 + reg;
                    const int pcg = w0 + res + 8 * m;     // global pot col
                    const bool valid = (fm < FM) && (pcg <= 2007);
                    const bool need = valid && (__builtin_fabsf(v - THRESH) < MARGIN);
                    unsigned long long bm = __ballot(need);
                    while (bm) {
                        const int src = __ffsll((long long)bm) - 1;
                        bm &= bm - 1;
                        const int q_s   = src >> 4;
                        const int fm_s  = ft * 16 + (src & 15);
                        const int pcg_s = w0 + res + 8 * (q_s * 4 + reg);
                        float part = 0.f;
#pragma unroll
                        for (int k2 = 0; k2 < 4; ++k2) {
                            const int t = L + 64 * k2;
                            if (t < 240) {
                                const int r2 = t / 40, c2 = t - 40 * r2;
                                part = fmaf(
                                    x[((size_t)tt * H_ + rowbase + j_p + r2) * WD_ + pcg_s + c2],
                                    Wg[(size_t)sec * FM * 240 + (size_t)fm_s * 240 + t],
                                    part);
                            }
                        }
#pragma unroll
                        for (int off = 32; off; off >>= 1)
                            part += __shfl_xor(part, off);
                        if (L == src) v = part;
                    }
                    if (valid && v > THRESH)
                        mask |= 1u << (reg * 8 + ft * 2 + (res >> 2));
                }
            };
            epilogue(acc0, S);
            epilogue(acc1, S + 4);
        }
    }

    unsigned* lmask = reinterpret_cast<unsigned*>(sred);
    lmask[j_p * 64 + L] = mask;
    __syncthreads();

    // ---- cross-wave OR + pooled write + fused first-spike argmin ----
    int mykey = 0x7fffffff;
    for (int e = tid; e < 2048; e += 256) {
        const int fmo = e >> 5, p = e & 31;
        const int m = p >> 1, rg = p & 1, ftc = fmo >> 4, fn = fmo & 15;
        const int lane = (m >> 2) * 16 + fn;
        const int bitpos = (m & 3) * 8 + ftc * 2 + rg;
        const unsigned bits = lmask[0 * 64 + lane] | lmask[1 * 64 + lane] |
                              lmask[2 * 64 + lane] | lmask[3 * 64 + lane];
        const int pg = coltile * 32 + p;
        const int spk = (bits >> bitpos) & 1u;
        if (fmo < FM && pg < WP) {
            out[((size_t)(sec * T_ + tt) * FM + fmo) * WP + pg] = spk ? 1.0f : 0.0f;
            if (spk) mykey = min(mykey, fmo * WP + pg);   // section-flat idx
        }
    }
    __syncthreads();                     // protect lmask -> red reuse
    sred[tid] = mykey;
    __syncthreads();
    for (int s = 128; s > 0; s >>= 1) {
        if (tid < s) sred[tid] = min(sred[tid], sred[tid + s]);
        __syncthreads();
    }
    if (tid == 0 && sred[0] != 0x7fffffff)
        atomicMin(&keys[sec], (tt << 15) | sred[0]);
}

// ---------------- init (fallback only) ----------------
__global__ void init_kernel(int* __restrict__ ws)
{
    if (threadIdx.x < NSEC) ws[threadIdx.x] = 0x7fffffff;
}

// ---------------- Kernel D: finalize winners ----------------
__global__ void finalize_kernel(const int* __restrict__ ws, float* __restrict__ out)
{
    const int i = threadIdx.x;
    if (i < NSEC) {
        const int key = ws[i];
        float feat;
        if (key == 0x7fffffff) feat = -1.0f;
        else                   feat = (float)((key & 32767) / WP);
        out[POOLED_SIZE + i] = feat;
    }
}

extern "C" void kernel_launch(void* const* d_in, const int* in_sizes, int n_in,
                              void* d_out, int out_size, void* d_ws, size_t ws_size,
                              hipStream_t stream) {
    const float* x  = (const float*)d_in[0];
    const float* Wg = (const float*)d_in[1];
    float* out = (float*)d_out;
    int*   wsi = (int*)d_ws;
    uint4* wfh = (uint4*)((char*)d_ws + 256);

    const bool pre = ws_size >= 256 + (size_t)NFRAG * 16;   // ~295 KB
    if (pre) {
        prep_kernel<<<dim3(72), dim3(256), 0, stream>>>(Wg, wsi, wfh);
        conv_pool_kernel<true><<<dim3(4320), dim3(256), 0, stream>>>(x, Wg, wfh, out, wsi);
    } else {
        init_kernel<<<dim3(1), dim3(64), 0, stream>>>(wsi);
        conv_pool_kernel<false><<<dim3(4320), dim3(256), 0, stream>>>(x, Wg, wfh, out, wsi);
    }
    finalize_kernel<<<dim3(1), dim3(16), 0, stream>>>(wsi, out);
}